// Round 1
// 860.979 us; speedup vs baseline: 1.0450x; 1.0450x over previous
//
#include <hip/hip_runtime.h>
#include <hip/hip_bf16.h>

#define V_PAD  30528
#define S_LEN  512
#define D_DIM  768
#define J_N    12
#define M_ROWS 1024
#define K_MLP  9984
#define N_MLP  9216
#define K_ATT  1536
#define N_ATT  768
#define N_LBL  7

using bf16x8 = __attribute__((ext_vector_type(8))) __bf16;
using f32x4  = __attribute__((ext_vector_type(4))) float;

__device__ __forceinline__ unsigned short f2bf(float f) {
  union { float f; unsigned int u; } c; c.f = f;
  unsigned int u = c.u;
  return (unsigned short)((u + 0x7fffu + ((u >> 16) & 1u)) >> 16); // RNE
}
__device__ __forceinline__ float bf2f(unsigned short h) {
  union { unsigned int u; float f; } c; c.u = (unsigned int)h << 16; return c.f;
}

// ---- fp32 -> bf16 bulk convert ----
__global__ __launch_bounds__(256)
void cvt_bf16_kernel(const float* __restrict__ in, unsigned short* __restrict__ out) {
  size_t i = (size_t)blockIdx.x * 256 + threadIdx.x;
  const float4 f0 = ((const float4*)in)[i * 2];
  const float4 f1 = ((const float4*)in)[i * 2 + 1];
  union { unsigned short h[8]; uint4 q; } pk;
  pk.h[0] = f2bf(f0.x); pk.h[1] = f2bf(f0.y); pk.h[2] = f2bf(f0.z); pk.h[3] = f2bf(f0.w);
  pk.h[4] = f2bf(f1.x); pk.h[5] = f2bf(f1.y); pk.h[6] = f2bf(f1.z); pk.h[7] = f2bf(f1.w);
  ((uint4*)out)[i] = pk.q;
}

// ---- last-occurrence tables (dict semantics) ----
__global__ void build_tables_kernel(const int* __restrict__ ids,
                                    int* __restrict__ last0,
                                    int* __restrict__ last01) {
  int p = blockIdx.x * 256 + threadIdx.x;
  if (p < M_ROWS) {
    int id = ids[p];
    atomicMax(&last01[id], p);
    if (p < S_LEN) atomicMax(&last0[id], p);
  }
}

// ---- seq -> rij[:, 0:768] bf16 ----
__global__ __launch_bounds__(256) void seqrij_kernel(const float* __restrict__ seq,
                                                     unsigned short* __restrict__ rij) {
  int bs = blockIdx.x;
  for (int d = threadIdx.x; d < D_DIM; d += 256)
    rij[(size_t)bs * K_MLP + d] = f2bf(seq[(size_t)bs * D_DIM + d]);
}

// ---- neighbor gather-sum -> rij[:, 768:] bf16 (+ nflat fp32 for fallback) ----
template <bool WRITE_NFLAT>
__global__ __launch_bounds__(192)
void gather_kernel(const float* __restrict__ seq, const int* __restrict__ nbr,
                   const int* __restrict__ last0, const int* __restrict__ last01,
                   float* __restrict__ nflat, unsigned short* __restrict__ rij) {
  const int bsj = blockIdx.x;
  const int j  = bsj % J_N;
  const int bs = bsj / J_N;
  const int b  = bs >> 9;
  const int* nb = nbr + (size_t)bsj * 4;
  const int* tab = (b == 0) ? last0 : last01;
  const int s0 = tab[nb[0]], s1 = tab[nb[1]], s2 = tab[nb[2]], s3 = tab[nb[3]];
  const int d4 = threadIdx.x;            // 0..191, covers 768 floats as float4
  float4 a = {0.f, 0.f, 0.f, 0.f};
  if (s0 >= 0) { float4 v = ((const float4*)(seq + (size_t)s0 * D_DIM))[d4]; a.x += v.x; a.y += v.y; a.z += v.z; a.w += v.w; }
  if (s1 >= 0) { float4 v = ((const float4*)(seq + (size_t)s1 * D_DIM))[d4]; a.x += v.x; a.y += v.y; a.z += v.z; a.w += v.w; }
  if (s2 >= 0) { float4 v = ((const float4*)(seq + (size_t)s2 * D_DIM))[d4]; a.x += v.x; a.y += v.y; a.z += v.z; a.w += v.w; }
  if (s3 >= 0) { float4 v = ((const float4*)(seq + (size_t)s3 * D_DIM))[d4]; a.x += v.x; a.y += v.y; a.z += v.z; a.w += v.w; }
  union { unsigned short h[4]; unsigned long long q; } pk;
  pk.h[0] = f2bf(a.x); pk.h[1] = f2bf(a.y); pk.h[2] = f2bf(a.z); pk.h[3] = f2bf(a.w);
  *(unsigned long long*)(rij + (size_t)bs * K_MLP + D_DIM + j * D_DIM + d4 * 4) = pk.q;
  if (WRITE_NFLAT)
    ((float4*)(nflat + (size_t)bs * N_MLP + j * D_DIM))[d4] = a;
}

// ---- NT MFMA GEMM, TMxTN tile, BK=32.
// Round-3 structure: double-buffered LDS with prefetch-before-compute
// (T3 minimum-2-phase: ONE barrier per k-iter, stage latency hidden under
// MFMA), both-sides XOR bank-conflict swizzle (pre-swizzled global source
// for global_load_lds, swizzled ds_read slot), optional XCD n-panel
// grouping swizzle for B-panel L2 reuse.
// MODE 0: in-place sigmoid gate (fallback). MODE 1: tanh(acc+bias) -> outp.
// MODE 2: raw partial -> outp + bz*M*N (split-K; bias applied later).
template <int MODE, int TM, int TN, bool BF16B, bool SWZ>
__global__ __launch_bounds__(256)
void gemm_nt_kernel(const unsigned short* __restrict__ A,
                    const void* __restrict__ Wv,
                    const float* __restrict__ bias,
                    float* __restrict__ nflat_c,
                    float* __restrict__ outp,
                    int K, int N, int kchunk) {
  constexpr int FM = TM / 32;
  constexpr int FN = TN / 32;
  __shared__ unsigned short ldsA[2][TM * 32];
  __shared__ unsigned short ldsB[2][TN * 32];
  const int tid  = threadIdx.x;
  const int lane = tid & 63;
  const int w    = tid >> 6;

  int bx = blockIdx.x, by = blockIdx.y, bz = blockIdx.z;
  if (SWZ) {
    // HW round-robins linear block id over 8 XCDs (l&7). Remap so all
    // gridDim.x m-tiles of one (n-tile, kz) group run on ONE XCD, dispatched
    // together: the shared B-panel is fetched from HBM once, then L2-hit.
    // Bijection requires nblocks%8==0 and (gridDim.y*gridDim.z)%8==0.
    const unsigned l   = blockIdx.x + gridDim.x * (blockIdx.y + gridDim.y * blockIdx.z);
    const unsigned xcd = l & 7u;
    const unsigned c   = l >> 3;
    const unsigned gpx = (gridDim.y * gridDim.z) >> 3;   // groups per XCD
    const unsigned g   = xcd * gpx + c / gridDim.x;
    bx = (int)(c % gridDim.x);
    by = (int)(g % gridDim.y);
    bz = (int)(g / gridDim.y);
  }
  const int m0 = bx * TM;
  const int n0 = by * TN;
  const int kb = bz * kchunk;

  f32x4 acc[FM][FN];
#pragma unroll
  for (int i = 0; i < FM; ++i)
#pragma unroll
    for (int j = 0; j < FN; ++j) acc[i][j] = (f32x4){0.f, 0.f, 0.f, 0.f};

  const int lr  = lane >> 2;
  // Bank-conflict swizzle (both-sides, rule 21): LDS slot p of row r holds
  // global 16B chunk p ^ ((r>>1)&3). Staging pre-swizzles the GLOBAL column
  // (global_load_lds dest is lane-linear); reads use the matching slot.
  // Breaks the 8-way conflict (64B rows, 16-bank stride) down to 2-way (free).
  const int lcs = (((lane & 3) ^ ((lane >> 3) & 3)) * 8);   // staging src col (elems)
  const int wm = (w >> 1) * (TM / 2), wn = (w & 1) * (TN / 2);
  const int fr  = lane & 15;
  const int fc  = (((lane >> 4) ^ ((fr >> 1) & 3)) * 8);    // read slot (elems)

  auto stage = [&](int buf, int kk) {
#pragma unroll
    for (int q = 0; q < TM / 64; ++q) {   // A tile -> LDS
      const int r = w * (TM / 4) + q * 16;
      const unsigned short* gsrc = A + (size_t)(m0 + r + lr) * K + kk + lcs;
      __builtin_amdgcn_global_load_lds(
          (const __attribute__((address_space(1))) void*)gsrc,
          (__attribute__((address_space(3))) void*)(&ldsA[buf][r * 32]), 16, 0, 0);
    }
    if (BF16B) {
#pragma unroll
      for (int q = 0; q < TN / 64; ++q) { // B tile -> LDS (bf16)
        const int r = w * (TN / 4) + q * 16;
        const unsigned short* gsrc = (const unsigned short*)Wv +
                                     (size_t)(n0 + r + lr) * K + kk + lcs;
        __builtin_amdgcn_global_load_lds(
            (const __attribute__((address_space(1))) void*)gsrc,
            (__attribute__((address_space(3))) void*)(&ldsB[buf][r * 32]), 16, 0, 0);
      }
    } else {                              // fp32 W -> bf16 -> LDS (reg-staged)
      constexpr int EPT = TN / 8;
      constexpr int TPR = 32 / EPT;
      const int br = tid / TPR, bc = (tid % TPR) * EPT;
      const float* gsrc = (const float*)Wv + (size_t)(n0 + br) * K + kk + bc;
      const int brs = (br >> 1) & 3;
#pragma unroll
      for (int e = 0; e < EPT; e += 8) {
        union { unsigned short h[8]; uint4 q4; } pk;
#pragma unroll
        for (int e2 = 0; e2 < 8; e2 += 4) {
          float4 f = *(const float4*)(gsrc + e + e2);
          pk.h[e2]     = f2bf(f.x); pk.h[e2 + 1] = f2bf(f.y);
          pk.h[e2 + 2] = f2bf(f.z); pk.h[e2 + 3] = f2bf(f.w);
        }
        const int slot = ((bc + e) >> 3) ^ brs;   // swizzled write slot
        *(uint4*)&ldsB[buf][br * 32 + slot * 8] = pk.q4;
      }
    }
  };

  const int nt = kchunk >> 5;   // k-iters (BK=32)
  stage(0, kb);                 // prologue
  for (int t = 0; t < nt; ++t) {
    const int cur = t & 1;
    // __syncthreads drains vmcnt(0)+lgkmcnt(0): buf[cur]'s stage (issued
    // last iter, latency hidden under last iter's MFMA) is complete, and all
    // waves' reads of buf[cur^1] are done before we overwrite it below.
    __syncthreads();
    if (t + 1 < nt) stage(cur ^ 1, kb + (t + 1) * 32);
    bf16x8 aF[FM], bF[FN];
#pragma unroll
    for (int i = 0; i < FM; ++i)
      aF[i] = *(const bf16x8*)&ldsA[cur][(wm + i * 16 + fr) * 32 + fc];
#pragma unroll
    for (int j = 0; j < FN; ++j)
      bF[j] = *(const bf16x8*)&ldsB[cur][(wn + j * 16 + fr) * 32 + fc];
#pragma unroll
    for (int i = 0; i < FM; ++i)
#pragma unroll
      for (int j = 0; j < FN; ++j)
        acc[i][j] = __builtin_amdgcn_mfma_f32_16x16x32_bf16(aF[i], bF[j], acc[i][j], 0, 0, 0);
  }

  const size_t zoff = (MODE == 2) ? (size_t)bz * M_ROWS * N : 0;
  // C/D layout: col = lane&15, row = (lane>>4)*4 + reg  [m89/m91]
#pragma unroll
  for (int i = 0; i < FM; ++i) {
    int gm0 = m0 + wm + i * 16 + (lane >> 4) * 4;
#pragma unroll
    for (int j = 0; j < FN; ++j) {
      int gn = n0 + wn + j * 16 + (lane & 15);
      float bv = (MODE == 2) ? 0.f : bias[gn];
#pragma unroll
      for (int r = 0; r < 4; ++r) {
        size_t idx = (size_t)(gm0 + r) * N + gn;
        float x = acc[i][j][r] + bv;
        if (MODE == 0) {
          float gg = 1.0f / (1.0f + __expf(-x));
          nflat_c[idx] = gg * nflat_c[idx];
        } else if (MODE == 1) {
          outp[idx] = tanhf(x);
        } else {
          outp[zoff + idx] = x;
        }
      }
    }
  }
}

// ---- attention (big path): combine split-K partials + bias + sigmoid gate,
// then scores/softmax/mix; emit [mix|seq] bf16 ----
__global__ __launch_bounds__(256)
void attn_fused_kernel(const float* __restrict__ seq,
                       const float* __restrict__ p0, const float* __restrict__ p1,
                       const float* __restrict__ bmlp,
                       const unsigned short* __restrict__ rij,
                       unsigned short* __restrict__ combined) {
  __shared__ float sc[N_MLP];
  __shared__ float sq[D_DIM];
  __shared__ float ss[J_N];
  const int m = blockIdx.x;
  const int tid = threadIdx.x, lane = tid & 63, w = tid >> 6;
  for (int d = tid; d < D_DIM; d += 256) sq[d] = seq[(size_t)m * D_DIM + d];
  const float* q0 = p0 + (size_t)m * N_MLP;
  const float* q1 = p1 + (size_t)m * N_MLP;
  const unsigned short* nrow = rij + (size_t)m * K_MLP + D_DIM;
  for (int d = tid; d < N_MLP; d += 256) {
    float z = q0[d] + q1[d] + bmlp[d];
    float g = 1.0f / (1.0f + __expf(-z));
    sc[d] = g * bf2f(nrow[d]);
  }
  __syncthreads();
#pragma unroll
  for (int jj = 0; jj < 3; ++jj) {
    int j = w * 3 + jj;
    float p = 0.f;
    for (int d = lane; d < D_DIM; d += 64) p += sq[d] * sc[j * D_DIM + d];
#pragma unroll
    for (int off = 32; off > 0; off >>= 1) p += __shfl_down(p, off);
    if (lane == 0) ss[j] = p;
  }
  __syncthreads();
  float mx = ss[0];
#pragma unroll
  for (int j = 1; j < J_N; ++j) mx = fmaxf(mx, ss[j]);
  float aw[J_N]; float sum = 0.f;
#pragma unroll
  for (int j = 0; j < J_N; ++j) { aw[j] = __expf(ss[j] - mx); sum += aw[j]; }
  float inv = 1.f / sum;
  for (int d = tid; d < D_DIM; d += 256) {
    float mix = 0.f;
#pragma unroll
    for (int j = 0; j < J_N; ++j) mix += aw[j] * sc[j * D_DIM + d];
    combined[(size_t)m * K_ATT + d]         = f2bf(mix * inv);
    combined[(size_t)m * K_ATT + D_DIM + d] = f2bf(sq[d]);
  }
}

// ---- attention (fallback path): c precomputed in nflat_c ----
__global__ __launch_bounds__(256)
void attn_kernel(const float* __restrict__ seq, const float* __restrict__ c,
                 unsigned short* __restrict__ combined) {
  __shared__ float sc[N_MLP];
  __shared__ float sq[D_DIM];
  __shared__ float ss[J_N];
  const int m = blockIdx.x;
  const int tid = threadIdx.x, lane = tid & 63, w = tid >> 6;
  const float* crow = c + (size_t)m * N_MLP;
  for (int d = tid; d < N_MLP; d += 256) sc[d] = crow[d];
  for (int d = tid; d < D_DIM; d += 256) sq[d] = seq[(size_t)m * D_DIM + d];
  __syncthreads();
#pragma unroll
  for (int jj = 0; jj < 3; ++jj) {
    int j = w * 3 + jj;
    float p = 0.f;
    for (int d = lane; d < D_DIM; d += 64) p += sq[d] * sc[j * D_DIM + d];
#pragma unroll
    for (int off = 32; off > 0; off >>= 1) p += __shfl_down(p, off);
    if (lane == 0) ss[j] = p;
  }
  __syncthreads();
  float mx = ss[0];
#pragma unroll
  for (int j = 1; j < J_N; ++j) mx = fmaxf(mx, ss[j]);
  float aw[J_N]; float sum = 0.f;
#pragma unroll
  for (int j = 0; j < J_N; ++j) { aw[j] = __expf(ss[j] - mx); sum += aw[j]; }
  float inv = 1.f / sum;
  for (int d = tid; d < D_DIM; d += 256) {
    float mix = 0.f;
#pragma unroll
    for (int j = 0; j < J_N; ++j) mix += aw[j] * sc[j * D_DIM + d];
    combined[(size_t)m * K_ATT + d]         = f2bf(mix * inv);
    combined[(size_t)m * K_ATT + D_DIM + d] = f2bf(sq[d]);
  }
}

// ---- classifier (shuffle-reduce) ----
__global__ __launch_bounds__(256)
void cls_kernel(const float* __restrict__ seq, const float* __restrict__ attnout,
                const float* __restrict__ Wc, const float* __restrict__ bc,
                float* __restrict__ out) {
  __shared__ float part[4][N_LBL];
  const int m = blockIdx.x, tid = threadIdx.x, lane = tid & 63, w = tid >> 6;
  float p[N_LBL] = {0.f, 0.f, 0.f, 0.f, 0.f, 0.f, 0.f};
  for (int f = tid; f < K_ATT; f += 256) {
    float v = (f < D_DIM) ? seq[(size_t)m * D_DIM + f]
                          : attnout[(size_t)m * D_DIM + (f - D_DIM)];
#pragma unroll
    for (int l = 0; l < N_LBL; ++l) p[l] += v * Wc[l * K_ATT + f];
  }
#pragma unroll
  for (int l = 0; l < N_LBL; ++l) {
#pragma unroll
    for (int off = 32; off > 0; off >>= 1) p[l] += __shfl_down(p[l], off);
  }
  if (lane == 0) {
#pragma unroll
    for (int l = 0; l < N_LBL; ++l) part[w][l] = p[l];
  }
  __syncthreads();
  if (tid < N_LBL)
    out[(size_t)m * N_LBL + tid] =
        part[0][tid] + part[1][tid] + part[2][tid] + part[3][tid] + bc[tid];
}

extern "C" void kernel_launch(void* const* d_in, const int* in_sizes, int n_in,
                              void* d_out, int out_size, void* d_ws, size_t ws_size,
                              hipStream_t stream) {
  const float* seq   = (const float*)d_in[0];
  const int*   ids   = (const int*)d_in[1];
  const int*   nbr   = (const int*)d_in[2];
  const float* Wmlp  = (const float*)d_in[3];
  const float* bmlp  = (const float*)d_in[4];
  const float* Wattn = (const float*)d_in[5];
  const float* battn = (const float*)d_in[6];
  const float* Wcls  = (const float*)d_in[7];
  const float* bcls  = (const float*)d_in[8];
  float* out = (float*)d_out;

  // Common workspace prefix
  char* ws = (char*)d_ws;
  size_t off = 0;
  int* last0  = (int*)(ws + off); off += (size_t)V_PAD * 4;
  int* last01 = (int*)(ws + off); off += (size_t)V_PAD * 4;
  unsigned short* rij = (unsigned short*)(ws + off); off += (size_t)M_ROWS * K_MLP * 2;
  unsigned short* combined = (unsigned short*)(ws + off); off += (size_t)M_ROWS * K_ATT * 2;
  float* attnout = (float*)(ws + off); off += (size_t)M_ROWS * N_ATT * 4;
  const size_t common = off;

  // big: split-K=2 partials, no nflat
  size_t ob = common;
  unsigned short* Wb_mlp  = (unsigned short*)(ws + ob); ob += (size_t)N_MLP * K_MLP * 2;
  unsigned short* Wb_attn = (unsigned short*)(ws + ob); ob += (size_t)N_ATT * K_ATT * 2;
  float* p0 = (float*)(ws + ob); ob += (size_t)M_ROWS * N_MLP * 4;
  float* p1 = (float*)(ws + ob); ob += (size_t)M_ROWS * N_MLP * 4;
  // mid (round-2 proven): nflat + bf16 weights
  size_t om = common;
  float* nflat_m = (float*)(ws + om); om += (size_t)M_ROWS * N_MLP * 4;
  unsigned short* Wm_mlp  = (unsigned short*)(ws + om); om += (size_t)N_MLP * K_MLP * 2;
  unsigned short* Wm_attn = (unsigned short*)(ws + om); om += (size_t)N_ATT * K_ATT * 2;
  // small: nflat only, fp32 W on the fly
  size_t os = common + (size_t)M_ROWS * N_MLP * 4;

  hipMemsetAsync(last0, 0xFF, (size_t)2 * V_PAD * 4, stream);
  build_tables_kernel<<<(M_ROWS + 255) / 256, 256, 0, stream>>>(ids, last0, last01);
  seqrij_kernel<<<M_ROWS, 256, 0, stream>>>(seq, rij);

  if (ws_size >= ob) {
    gather_kernel<false><<<M_ROWS * J_N, 192, 0, stream>>>(seq, nbr, last0, last01, nullptr, rij);
    cvt_bf16_kernel<<<(N_MLP * K_MLP) / (256 * 8), 256, 0, stream>>>(Wmlp, Wb_mlp);
    cvt_bf16_kernel<<<(N_ATT * K_ATT) / (256 * 8), 256, 0, stream>>>(Wattn, Wb_attn);
    // MLP GEMM: 128x128 tile, split-K=2 -> raw partials. SWZ groups the 8
    // m-tiles of each (n,kz) panel onto one XCD for B L2 reuse.
    gemm_nt_kernel<2, 128, 128, true, true><<<dim3(M_ROWS / 128, N_MLP / 128, 2), 256, 0, stream>>>(
        rij, Wb_mlp, nullptr, nullptr, p0, K_MLP, N_MLP, K_MLP / 2);
    attn_fused_kernel<<<M_ROWS, 256, 0, stream>>>(seq, p0, p1, bmlp, rij, combined);
    gemm_nt_kernel<1, 64, 64, true, false><<<dim3(M_ROWS / 64, N_ATT / 64), 256, 0, stream>>>(
        combined, Wb_attn, battn, nullptr, attnout, K_ATT, N_ATT, K_ATT);
  } else if (ws_size >= om) {
    gather_kernel<true><<<M_ROWS * J_N, 192, 0, stream>>>(seq, nbr, last0, last01, nflat_m, rij);
    cvt_bf16_kernel<<<(N_MLP * K_MLP) / (256 * 8), 256, 0, stream>>>(Wmlp, Wm_mlp);
    cvt_bf16_kernel<<<(N_ATT * K_ATT) / (256 * 8), 256, 0, stream>>>(Wattn, Wm_attn);
    gemm_nt_kernel<0, 128, 64, true, true><<<dim3(M_ROWS / 128, N_MLP / 64), 256, 0, stream>>>(
        rij, Wm_mlp, bmlp, nflat_m, nullptr, K_MLP, N_MLP, K_MLP);
    attn_kernel<<<M_ROWS, 256, 0, stream>>>(seq, nflat_m, combined);
    gemm_nt_kernel<1, 64, 64, true, false><<<dim3(M_ROWS / 64, N_ATT / 64), 256, 0, stream>>>(
        combined, Wm_attn, battn, nullptr, attnout, K_ATT, N_ATT, K_ATT);
  } else {
    float* nflat_s = nflat_m;  // same offset, no bf16 weights after it
    (void)os;
    gather_kernel<true><<<M_ROWS * J_N, 192, 0, stream>>>(seq, nbr, last0, last01, nflat_s, rij);
    gemm_nt_kernel<0, 128, 64, false, true><<<dim3(M_ROWS / 128, N_MLP / 64), 256, 0, stream>>>(
        rij, Wmlp, bmlp, nflat_s, nullptr, K_MLP, N_MLP, K_MLP);
    attn_kernel<<<M_ROWS, 256, 0, stream>>>(seq, nflat_s, combined);
    gemm_nt_kernel<1, 64, 64, false, false><<<dim3(M_ROWS / 64, N_ATT / 64), 256, 0, stream>>>(
        combined, Wattn, battn, nullptr, attnout, K_ATT, N_ATT, K_ATT);
  }
  cls_kernel<<<M_ROWS, 256, 0, stream>>>(seq, attnout, Wcls, bcls, out);
}